// Round 5
// baseline (78.164 us; speedup 1.0000x reference)
//
#include <hip/hip_runtime.h>
#include <math.h>

#define B_    128
#define S_    2048
#define FEAT_ 512
#define DK_   64
#define NSPLIT 32
#define CHUNK  (S_ / NSPLIT)   // 64 rows per split; 16 rows per wave

typedef float f32x4 __attribute__((ext_vector_type(4)));

#define SBAR() __builtin_amdgcn_sched_barrier(0)
#define VWAIT(N)                                                  \
  do {                                                            \
    asm volatile("s_waitcnt vmcnt(" #N ")" ::: "memory");         \
    SBAR();                                                       \
  } while (0)
#define LWAIT()                                                   \
  do {                                                            \
    asm volatile("s_waitcnt lgkmcnt(0)" ::: "memory");            \
    SBAR();                                                       \
  } while (0)

// async global->LDS, 16B/lane: lane l's 16B from g+l*4 floats lands at
// lds_base + l*16 (wave-uniform base, HW scatters lane*16).
__device__ __forceinline__ void glds16(const float* g, float* l) {
  __builtin_amdgcn_global_load_lds(
      (const __attribute__((address_space(1))) void*)g,
      (__attribute__((address_space(3))) void*)l, 16, 0, 0);
}

__device__ __forceinline__ float dot8(f32x4 x0, f32x4 x1, f32x4 v0, f32x4 v1) {
  float p = x0[0] * v0[0];
  p = fmaf(x0[1], v0[1], p);
  p = fmaf(x0[2], v0[2], p);
  p = fmaf(x0[3], v0[3], p);
  p = fmaf(x1[0], v1[0], p);
  p = fmaf(x1[1], v1[1], p);
  p = fmaf(x1[2], v1[2], p);
  p = fmaf(x1[3], v1[3], p);
  return p;
}

__device__ __forceinline__ float wredsum(float p) {
#pragma unroll
  for (int off = 32; off; off >>= 1) p += __shfl_xor(p, off, 64);
  return p;
}

// online-softmax update with two rows (xA0,xA1) and (xB0,xB1)
__device__ __forceinline__ void math2(
    f32x4 xA0, f32x4 xA1, f32x4 xB0, f32x4 xB1,
    f32x4 v0, f32x4 v1, float& m, float& l, f32x4& a0, f32x4& a1) {
  float p0 = dot8(xA0, xA1, v0, v1);
  float p1 = dot8(xB0, xB1, v0, v1);
  p0 = wredsum(p0);
  p1 = wredsum(p1);
  float mn = fmaxf(m, fmaxf(p0, p1));
  float sc = __expf(m - mn);   // first group: exp(-inf) = 0
  float w0 = __expf(p0 - mn);
  float w1 = __expf(p1 - mn);
  l = fmaf(l, sc, w0 + w1);
#pragma unroll
  for (int j = 0; j < 4; ++j) {
    a0[j] = fmaf(w0, xA0[j], fmaf(w1, xB0[j], a0[j] * sc));
    a1[j] = fmaf(w0, xA1[j], fmaf(w1, xB1[j], a1[j] * sc));
  }
  m = mn;
}

// ---------------------------------------------------------------------------
// Kernel 1: v[b,f] = sum_d W_K[f,d] * (input_q[b] @ W_Q)[d]
// ---------------------------------------------------------------------------
__global__ __launch_bounds__(256) void qv_kernel(
    const float* __restrict__ input_q, const float* __restrict__ W_Q,
    const float* __restrict__ W_K, float* __restrict__ v) {
  int b = blockIdx.x;
  int tid = threadIdx.x;
  __shared__ float xq[FEAT_];
  __shared__ float part[4][DK_];
  __shared__ float qs[DK_];
  for (int f = tid; f < FEAT_; f += 256) xq[f] = input_q[b * FEAT_ + f];
  __syncthreads();
  {
    int d = tid & 63, c = tid >> 6;
    float s = 0.f;
    int f0 = c * 128;
    for (int f = f0; f < f0 + 128; ++f) s = fmaf(xq[f], W_Q[f * DK_ + d], s);
    part[c][d] = s;
  }
  __syncthreads();
  if (tid < DK_)
    qs[tid] = part[0][tid] + part[1][tid] + part[2][tid] + part[3][tid];
  __syncthreads();
  for (int f = tid; f < FEAT_; f += 256) {
    const f32x4* wk = (const f32x4*)(W_K + f * DK_);
    float s = 0.f;
#pragma unroll
    for (int d4 = 0; d4 < DK_ / 4; ++d4) {
      f32x4 w = wk[d4];
      s = fmaf(w[0], qs[d4 * 4 + 0], s);
      s = fmaf(w[1], qs[d4 * 4 + 1], s);
      s = fmaf(w[2], qs[d4 * 4 + 2], s);
      s = fmaf(w[3], qs[d4 * 4 + 3], s);
    }
    v[b * FEAT_ + f] = s;
  }
}

// ---------------------------------------------------------------------------
// Kernel 2: streaming pass. Full splits: per-wave double-buffered LDS staging
// via global_load_lds (zero data VGPRs in flight), counted vmcnt so 8 KB/wave
// stays outstanding through every compute window. No barriers in the loop
// (buffers are wave-private). Stage memory is reused as the cross-wave
// combine buffer afterwards.
// ---------------------------------------------------------------------------
__global__ __launch_bounds__(256) void pass_kernel(
    const float* __restrict__ input_k, const int* __restrict__ ctx,
    const float* __restrict__ v, float* __restrict__ pm,
    float* __restrict__ pl, float* __restrict__ pacc) {
  __shared__ __align__(16) float stage[4][2][1024];  // [wave][buf][2 rows]
  __shared__ float sm[4], sl[4];

  int split = blockIdx.x;
  int b = blockIdx.y;
  int L = ctx[b];
  int s0 = split * CHUNK;
  int tid = threadIdx.x, wave = tid >> 6, lane = tid & 63;
  int idx = b * NSPLIT + split;

  if (s0 >= L) {  // inactive split: no pacc write; combine skips e==0
    if (tid == 0) { pm[idx] = -INFINITY; pl[idx] = 0.f; }
    return;
  }

  const float* vb = v + b * FEAT_ + lane * 4;
  f32x4 v0 = *(const f32x4*)vb;
  f32x4 v1 = *(const f32x4*)(vb + 256);

  float m = -INFINITY, l = 0.f;
  f32x4 a0 = {0.f, 0.f, 0.f, 0.f};
  f32x4 a1 = {0.f, 0.f, 0.f, 0.f};

  const float* base = input_k + (size_t)b * S_ * FEAT_;
  float* st0 = &stage[wave][0][0];
  float* st1 = &stage[wave][1][0];

  if (L >= s0 + CHUNK) {
    // ---- full split: 16 rows/wave (s = s0+wave+4i), 8 groups of 2 rows ----
    const float* rb = base + (size_t)(s0 + wave) * FEAT_ + lane * 4;
    // group g: rows at float-offsets 4096*g and 4096*g + 2048 from rb
#define GISSUE(g_, st_)                                     \
    do {                                                    \
      const float* gp_ = rb + (size_t)4096 * (g_);          \
      glds16(gp_,        (st_));                            \
      glds16(gp_ + 256,  (st_) + 256);                      \
      glds16(gp_ + 2048, (st_) + 512);                      \
      glds16(gp_ + 2304, (st_) + 768);                      \
    } while (0)
#define LOAD2(st_, xA0, xA1, xB0, xB1)                      \
    do {                                                    \
      const f32x4* p_ = (const f32x4*)(st_) + lane;         \
      xA0 = p_[0];                                          \
      xA1 = p_[64];                                         \
      xB0 = p_[128];                                        \
      xB1 = p_[192];                                        \
    } while (0)

    GISSUE(0, st0);
    GISSUE(1, st1);
    VWAIT(0);
#pragma unroll
    for (int g = 0; g < 6; ++g) {
      float* cur = (g & 1) ? st1 : st0;
      f32x4 xA0, xA1, xB0, xB1;
      LOAD2(cur, xA0, xA1, xB0, xB1);
      LWAIT();                 // reads in regs before overwrite (WAR)
      GISSUE(g + 2, cur);      // prefetch 2 groups ahead
      math2(xA0, xA1, xB0, xB1, v0, v1, m, l, a0, a1);
      VWAIT(4);                // group g+1 landed (RAW for next iter)
    }
    {  // g = 6 (buf0 ready via the last VWAIT(4); G7 still in flight)
      f32x4 xA0, xA1, xB0, xB1;
      LOAD2(st0, xA0, xA1, xB0, xB1);
      math2(xA0, xA1, xB0, xB1, v0, v1, m, l, a0, a1);
    }
    VWAIT(0);                  // G7 landed
    {  // g = 7
      f32x4 xA0, xA1, xB0, xB1;
      LOAD2(st1, xA0, xA1, xB0, xB1);
      math2(xA0, xA1, xB0, xB1, v0, v1, m, l, a0, a1);
    }
#undef GISSUE
#undef LOAD2
  } else {
    // ---- partial split (≤1 per batch): plain loads, 2-row groups ----
    int s = s0 + wave;
    for (; s + 4 < L; s += 8) {
      const float* r_ = base + (size_t)s * FEAT_ + lane * 4;
      f32x4 xA0 = *(const f32x4*)(r_);
      f32x4 xA1 = *(const f32x4*)(r_ + 256);
      f32x4 xB0 = *(const f32x4*)(r_ + 4 * FEAT_);
      f32x4 xB1 = *(const f32x4*)(r_ + 4 * FEAT_ + 256);
      math2(xA0, xA1, xB0, xB1, v0, v1, m, l, a0, a1);
    }
    if (s < L) {
      const float* r_ = base + (size_t)s * FEAT_ + lane * 4;
      f32x4 x0 = *(const f32x4*)(r_);
      f32x4 x1 = *(const f32x4*)(r_ + 256);
      float p = wredsum(dot8(x0, x1, v0, v1));
      float mn = fmaxf(m, p);
      float sc = __expf(m - mn);
      float w = __expf(p - mn);
      l = fmaf(l, sc, w);
#pragma unroll
      for (int j = 0; j < 4; ++j) {
        a0[j] = fmaf(w, x0[j], a0[j] * sc);
        a1[j] = fmaf(w, x1[j], a1[j] * sc);
      }
      m = mn;
    }
  }

  // ---- cross-wave combine; reuse stage[wave][0] as the partial buffer ----
  if (lane == 0) { sm[wave] = m; sl[wave] = l; }
  {
    f32x4* sw = (f32x4*)&stage[wave][0][0];
    sw[lane] = a0;        // floats [4*lane ..]
    sw[64 + lane] = a1;   // floats [256 + 4*lane ..]
  }
  __syncthreads();

  float M = fmaxf(fmaxf(sm[0], sm[1]), fmaxf(sm[2], sm[3]));
  float e0 = __expf(sm[0] - M), e1 = __expf(sm[1] - M);
  float e2 = __expf(sm[2] - M), e3 = __expf(sm[3] - M);
  if (tid == 0) {
    pm[idx] = M;
    pl[idx] = e0 * sl[0] + e1 * sl[1] + e2 * sl[2] + e3 * sl[3];
  }
  for (int f = tid; f < FEAT_; f += 256)
    pacc[(size_t)idx * FEAT_ + f] =
        e0 * stage[0][0][f] + e1 * stage[1][0][f] +
        e2 * stage[2][0][f] + e3 * stage[3][0][f];
}

// ---------------------------------------------------------------------------
// Kernel 3: combine partials per batch, normalize, zero L==0 rows.
// ---------------------------------------------------------------------------
__global__ __launch_bounds__(256) void combine_kernel(
    const float* __restrict__ pm, const float* __restrict__ pl,
    const float* __restrict__ pacc, float* __restrict__ out) {
  int b = blockIdx.x;
  int tid = threadIdx.x;
  __shared__ float e[NSPLIT];
  __shared__ float inv_s;
  if (tid < NSPLIT) {  // lanes 0..31 of wave 0
    float mi = pm[b * NSPLIT + tid];
    float M = mi;
#pragma unroll
    for (int off = 16; off; off >>= 1) M = fmaxf(M, __shfl_xor(M, off, 64));
    float ei = (M == -INFINITY) ? 0.f : __expf(mi - M);
    e[tid] = ei;
    float lw = ei * pl[b * NSPLIT + tid];
#pragma unroll
    for (int off = 16; off; off >>= 1) lw += __shfl_xor(lw, off, 64);
    if (tid == 0) inv_s = (lw > 0.f) ? 1.f / lw : 0.f;  // L==0 -> zeros
  }
  __syncthreads();
  float inv = inv_s;
  for (int f = tid; f < FEAT_; f += 256) {
    float s = 0.f;
    for (int i = 0; i < NSPLIT; ++i)
      if (e[i] > 0.f)   // block-uniform; skips loads of never-written pacc
        s = fmaf(e[i], pacc[((size_t)(b * NSPLIT + i)) * FEAT_ + f], s);
    out[b * FEAT_ + f] = s * inv;
  }
}

extern "C" void kernel_launch(void* const* d_in, const int* in_sizes, int n_in,
                              void* d_out, int out_size, void* d_ws, size_t ws_size,
                              hipStream_t stream) {
  const float* input_k = (const float*)d_in[0];
  const float* input_q = (const float*)d_in[1];
  const int*   ctx     = (const int*)d_in[2];
  const float* W_K     = (const float*)d_in[3];
  const float* W_Q     = (const float*)d_in[4];
  float* out = (float*)d_out;

  char* ws = (char*)d_ws;
  float* v    = (float*)ws;                                   // B*FEAT
  float* pm   = (float*)(ws + (size_t)B_ * FEAT_ * sizeof(float));
  float* pl   = pm + B_ * NSPLIT;
  float* pacc = pl + B_ * NSPLIT;                             // B*NSPLIT*FEAT

  qv_kernel<<<B_, 256, 0, stream>>>(input_q, W_Q, W_K, v);
  pass_kernel<<<dim3(NSPLIT, B_), 256, 0, stream>>>(input_k, ctx, v, pm, pl, pacc);
  combine_kernel<<<B_, 256, 0, stream>>>(pm, pl, pacc, out);
}

// Round 6
// 78.054 us; speedup vs baseline: 1.0014x; 1.0014x over previous
//
#include <hip/hip_runtime.h>
#include <math.h>

#define B_    128
#define S_    2048
#define FEAT_ 512
#define DK_   64
#define NSPLIT 32
#define RSTRIDE (NSPLIT * FEAT_)   // floats between consecutive rows of a split

typedef float f32x4 __attribute__((ext_vector_type(4)));

__device__ __forceinline__ float dot8(f32x4 x0, f32x4 x1, f32x4 v0, f32x4 v1) {
  float p = x0[0] * v0[0];
  p = fmaf(x0[1], v0[1], p);
  p = fmaf(x0[2], v0[2], p);
  p = fmaf(x0[3], v0[3], p);
  p = fmaf(x1[0], v1[0], p);
  p = fmaf(x1[1], v1[1], p);
  p = fmaf(x1[2], v1[2], p);
  p = fmaf(x1[3], v1[3], p);
  return p;
}

__device__ __forceinline__ float wredsum(float p) {
#pragma unroll
  for (int off = 32; off; off >>= 1) p += __shfl_xor(p, off, 64);
  return p;
}

// ---------------------------------------------------------------------------
// Kernel 1: v[b,f] = sum_d W_K[f,d] * (input_q[b] @ W_Q)[d]
// ---------------------------------------------------------------------------
__global__ __launch_bounds__(256) void qv_kernel(
    const float* __restrict__ input_q, const float* __restrict__ W_Q,
    const float* __restrict__ W_K, float* __restrict__ v) {
  int b = blockIdx.x;
  int tid = threadIdx.x;
  __shared__ float xq[FEAT_];
  __shared__ float part[4][DK_];
  __shared__ float qs[DK_];
  for (int f = tid; f < FEAT_; f += 256) xq[f] = input_q[b * FEAT_ + f];
  __syncthreads();
  {
    int d = tid & 63, c = tid >> 6;
    float s = 0.f;
    int f0 = c * 128;
    for (int f = f0; f < f0 + 128; ++f) s = fmaf(xq[f], W_Q[f * DK_ + d], s);
    part[c][d] = s;
  }
  __syncthreads();
  if (tid < DK_)
    qs[tid] = part[0][tid] + part[1][tid] + part[2][tid] + part[3][tid];
  __syncthreads();
  for (int f = tid; f < FEAT_; f += 256) {
    const f32x4* wk = (const f32x4*)(W_K + f * DK_);
    float s = 0.f;
#pragma unroll
    for (int d4 = 0; d4 < DK_ / 4; ++d4) {
      f32x4 w = wk[d4];
      s = fmaf(w[0], qs[d4 * 4 + 0], s);
      s = fmaf(w[1], qs[d4 * 4 + 1], s);
      s = fmaf(w[2], qs[d4 * 4 + 2], s);
      s = fmaf(w[3], qs[d4 * 4 + 3], s);
    }
    v[b * FEAT_ + f] = s;
  }
}

// ---------------------------------------------------------------------------
// Kernel 2: streaming pass, STRIDED split mapping: split j owns rows
// {s : s % 32 == j, s < L} -> all splits of a batch have equal work (+-1 row),
// no dead blocks for L>0, work per block proportional to L_b.
// Body is the proven R2 loop (4-row unroll, online softmax).
// ---------------------------------------------------------------------------
__global__ __launch_bounds__(256) void pass_kernel(
    const float* __restrict__ input_k, const int* __restrict__ ctx,
    const float* __restrict__ v, float* __restrict__ pm,
    float* __restrict__ pl, float* __restrict__ pacc) {
  int split = blockIdx.x;
  int b = blockIdx.y;
  int L = ctx[b];
  int tid = threadIdx.x, wave = tid >> 6, lane = tid & 63;
  int idx = b * NSPLIT + split;

  if (split >= L) {  // inactive (only when L < 32); combine skips e==0
    if (tid == 0) { pm[idx] = -INFINITY; pl[idx] = 0.f; }
    return;
  }
  int nt = (L - split + NSPLIT - 1) / NSPLIT;  // rows owned by this split

  const float* vb = v + b * FEAT_ + lane * 4;
  f32x4 v0 = *(const f32x4*)vb;
  f32x4 v1 = *(const f32x4*)(vb + 256);

  float m = -INFINITY, l = 0.f;
  f32x4 a0 = {0.f, 0.f, 0.f, 0.f};
  f32x4 a1 = {0.f, 0.f, 0.f, 0.f};

  // row t (t=0..nt-1) lives at base + t*RSTRIDE
  const float* base = input_k + (size_t)b * S_ * FEAT_ + split * FEAT_ + lane * 4;

  int t = wave;
  // main loop: 4 rows per iteration (t, t+4, t+8, t+12)
  for (; t + 12 < nt; t += 16) {
    const float* r_ = base + (size_t)t * RSTRIDE;
    f32x4 x0 = *(const f32x4*)(r_);
    f32x4 x1 = *(const f32x4*)(r_ + 256);
    f32x4 x2 = *(const f32x4*)(r_ + 4 * (size_t)RSTRIDE);
    f32x4 x3 = *(const f32x4*)(r_ + 4 * (size_t)RSTRIDE + 256);
    f32x4 x4 = *(const f32x4*)(r_ + 8 * (size_t)RSTRIDE);
    f32x4 x5 = *(const f32x4*)(r_ + 8 * (size_t)RSTRIDE + 256);
    f32x4 x6 = *(const f32x4*)(r_ + 12 * (size_t)RSTRIDE);
    f32x4 x7 = *(const f32x4*)(r_ + 12 * (size_t)RSTRIDE + 256);

    float p0 = dot8(x0, x1, v0, v1);
    float p1 = dot8(x2, x3, v0, v1);
    float p2 = dot8(x4, x5, v0, v1);
    float p3 = dot8(x6, x7, v0, v1);
    p0 = wredsum(p0);
    p1 = wredsum(p1);
    p2 = wredsum(p2);
    p3 = wredsum(p3);
    float mn = fmaxf(fmaxf(fmaxf(p0, p1), fmaxf(p2, p3)), m);
    float sc = __expf(m - mn);   // first group: exp(-inf)=0
    float w0 = __expf(p0 - mn), w1 = __expf(p1 - mn);
    float w2 = __expf(p2 - mn), w3 = __expf(p3 - mn);
    l = fmaf(l, sc, (w0 + w1) + (w2 + w3));
#pragma unroll
    for (int j = 0; j < 4; ++j) {
      a0[j] = fmaf(w0, x0[j],
              fmaf(w1, x2[j], fmaf(w2, x4[j], fmaf(w3, x6[j], a0[j] * sc))));
      a1[j] = fmaf(w0, x1[j],
              fmaf(w1, x3[j], fmaf(w2, x5[j], fmaf(w3, x7[j], a1[j] * sc))));
    }
    m = mn;
  }
  // tail: single row per step
  for (; t < nt; t += 4) {
    const float* r_ = base + (size_t)t * RSTRIDE;
    f32x4 x0 = *(const f32x4*)(r_);
    f32x4 x1 = *(const f32x4*)(r_ + 256);
    float p = wredsum(dot8(x0, x1, v0, v1));
    float mn = fmaxf(m, p);
    float sc = __expf(m - mn);
    float w = __expf(p - mn);
    l = fmaf(l, sc, w);
#pragma unroll
    for (int j = 0; j < 4; ++j) {
      a0[j] = fmaf(w, x0[j], a0[j] * sc);
      a1[j] = fmaf(w, x1[j], a1[j] * sc);
    }
    m = mn;
  }

  // cross-wave combine in LDS
  __shared__ float sm[4], sl[4];
  __shared__ float sa[4][FEAT_];
  if (lane == 0) { sm[wave] = m; sl[wave] = l; }
  *(f32x4*)&sa[wave][lane * 4] = a0;
  *(f32x4*)&sa[wave][256 + lane * 4] = a1;
  __syncthreads();

  float M = fmaxf(fmaxf(sm[0], sm[1]), fmaxf(sm[2], sm[3]));
  float e0 = __expf(sm[0] - M), e1 = __expf(sm[1] - M);
  float e2 = __expf(sm[2] - M), e3 = __expf(sm[3] - M);
  if (tid == 0) {
    pm[idx] = M;
    pl[idx] = e0 * sl[0] + e1 * sl[1] + e2 * sl[2] + e3 * sl[3];
  }
  for (int f = tid; f < FEAT_; f += 256)
    pacc[(size_t)idx * FEAT_ + f] =
        e0 * sa[0][f] + e1 * sa[1][f] + e2 * sa[2][f] + e3 * sa[3][f];
}

// ---------------------------------------------------------------------------
// Kernel 3: combine partials per batch, normalize, zero L==0 rows.
// ---------------------------------------------------------------------------
__global__ __launch_bounds__(256) void combine_kernel(
    const float* __restrict__ pm, const float* __restrict__ pl,
    const float* __restrict__ pacc, float* __restrict__ out) {
  int b = blockIdx.x;
  int tid = threadIdx.x;
  __shared__ float e[NSPLIT];
  __shared__ float inv_s;
  if (tid < NSPLIT) {  // lanes 0..31 of wave 0
    float mi = pm[b * NSPLIT + tid];
    float M = mi;
#pragma unroll
    for (int off = 16; off; off >>= 1) M = fmaxf(M, __shfl_xor(M, off, 64));
    float ei = (M == -INFINITY) ? 0.f : __expf(mi - M);
    e[tid] = ei;
    float lw = ei * pl[b * NSPLIT + tid];
#pragma unroll
    for (int off = 16; off; off >>= 1) lw += __shfl_xor(lw, off, 64);
    if (tid == 0) inv_s = (lw > 0.f) ? 1.f / lw : 0.f;  // L==0 -> zeros
  }
  __syncthreads();
  float inv = inv_s;
  for (int f = tid; f < FEAT_; f += 256) {
    float s = 0.f;
    for (int i = 0; i < NSPLIT; ++i)
      if (e[i] > 0.f)   // block-uniform; skips loads of never-written pacc
        s = fmaf(e[i], pacc[((size_t)(b * NSPLIT + i)) * FEAT_ + f], s);
    out[b * FEAT_ + f] = s * inv;
  }
}

extern "C" void kernel_launch(void* const* d_in, const int* in_sizes, int n_in,
                              void* d_out, int out_size, void* d_ws, size_t ws_size,
                              hipStream_t stream) {
  const float* input_k = (const float*)d_in[0];
  const float* input_q = (const float*)d_in[1];
  const int*   ctx     = (const int*)d_in[2];
  const float* W_K     = (const float*)d_in[3];
  const float* W_Q     = (const float*)d_in[4];
  float* out = (float*)d_out;

  char* ws = (char*)d_ws;
  float* v    = (float*)ws;                                   // B*FEAT
  float* pm   = (float*)(ws + (size_t)B_ * FEAT_ * sizeof(float));
  float* pl   = pm + B_ * NSPLIT;
  float* pacc = pl + B_ * NSPLIT;                             // B*NSPLIT*FEAT

  qv_kernel<<<B_, 256, 0, stream>>>(input_q, W_Q, W_K, v);
  pass_kernel<<<dim3(NSPLIT, B_), 256, 0, stream>>>(input_k, ctx, v, pm, pl, pacc);
  combine_kernel<<<B_, 256, 0, stream>>>(pm, pl, pacc, out);
}

// Round 7
// 67.192 us; speedup vs baseline: 1.1633x; 1.1617x over previous
//
#include <hip/hip_runtime.h>
#include <math.h>

#define B_    128
#define S_    2048
#define FEAT_ 512
#define DK_   64
#define NSPLIT 16

typedef float f32x4 __attribute__((ext_vector_type(4)));

__device__ __forceinline__ float dot8(f32x4 x0, f32x4 x1, f32x4 v0, f32x4 v1) {
  float p = x0[0] * v0[0];
  p = fmaf(x0[1], v0[1], p);
  p = fmaf(x0[2], v0[2], p);
  p = fmaf(x0[3], v0[3], p);
  p = fmaf(x1[0], v1[0], p);
  p = fmaf(x1[1], v1[1], p);
  p = fmaf(x1[2], v1[2], p);
  p = fmaf(x1[3], v1[3], p);
  return p;
}

__device__ __forceinline__ float wredsum(float p) {
#pragma unroll
  for (int off = 32; off; off >>= 1) p += __shfl_xor(p, off, 64);
  return p;
}

// ---------------------------------------------------------------------------
// Kernel 1: v[b,f] = sum_d W_K[f,d] * (input_q[b] @ W_Q)[d]
// ---------------------------------------------------------------------------
__global__ __launch_bounds__(256) void qv_kernel(
    const float* __restrict__ input_q, const float* __restrict__ W_Q,
    const float* __restrict__ W_K, float* __restrict__ v) {
  int b = blockIdx.x;
  int tid = threadIdx.x;
  __shared__ float xq[FEAT_];
  __shared__ float part[4][DK_];
  __shared__ float qs[DK_];
  for (int f = tid; f < FEAT_; f += 256) xq[f] = input_q[b * FEAT_ + f];
  __syncthreads();
  {
    int d = tid & 63, c = tid >> 6;
    float s = 0.f;
    int f0 = c * 128;
    for (int f = f0; f < f0 + 128; ++f) s = fmaf(xq[f], W_Q[f * DK_ + d], s);
    part[c][d] = s;
  }
  __syncthreads();
  if (tid < DK_)
    qs[tid] = part[0][tid] + part[1][tid] + part[2][tid] + part[3][tid];
  __syncthreads();
  for (int f = tid; f < FEAT_; f += 256) {
    const f32x4* wk = (const f32x4*)(W_K + f * DK_);
    float s = 0.f;
#pragma unroll
    for (int d4 = 0; d4 < DK_ / 4; ++d4) {
      f32x4 w = wk[d4];
      s = fmaf(w[0], qs[d4 * 4 + 0], s);
      s = fmaf(w[1], qs[d4 * 4 + 1], s);
      s = fmaf(w[2], qs[d4 * 4 + 2], s);
      s = fmaf(w[3], qs[d4 * 4 + 3], s);
    }
    v[b * FEAT_ + f] = s;
  }
}

// ---------------------------------------------------------------------------
// Kernel 2: streaming pass. BALANCED CONTIGUOUS split mapping: split j of
// batch b owns rows [ j*L/16, (j+1)*L/16 ) — equal work per block, zero dead
// blocks, and each wave streams rows at the same 8 KB stride as the proven
// R2 loop (DRAM-page friendly). Body identical to R2's champion loop.
// ---------------------------------------------------------------------------
__global__ __launch_bounds__(256) void pass_kernel(
    const float* __restrict__ input_k, const int* __restrict__ ctx,
    const float* __restrict__ v, float* __restrict__ pm,
    float* __restrict__ pl, float* __restrict__ pacc) {
  int split = blockIdx.x;
  int b = blockIdx.y;
  int L = ctx[b];
  int tid = threadIdx.x, wave = tid >> 6, lane = tid & 63;
  int idx = b * NSPLIT + split;

  int s0 = (split * L) / NSPLIT;
  int s1 = ((split + 1) * L) / NSPLIT;

  if (s0 >= s1) {  // empty share (only when L < NSPLIT); combine skips e==0
    if (tid == 0) { pm[idx] = -INFINITY; pl[idx] = 0.f; }
    return;
  }

  const float* vb = v + b * FEAT_ + lane * 4;
  f32x4 v0 = *(const f32x4*)vb;
  f32x4 v1 = *(const f32x4*)(vb + 256);

  float m = -INFINITY, l = 0.f;
  f32x4 a0 = {0.f, 0.f, 0.f, 0.f};
  f32x4 a1 = {0.f, 0.f, 0.f, 0.f};

  const float* base = input_k + (size_t)b * S_ * FEAT_;
  int s = s0 + wave;

  // main loop: 4 rows per iteration (s, s+4, s+8, s+12)
  for (; s + 12 < s1; s += 16) {
    const float* r_ = base + (size_t)s * FEAT_ + lane * 4;
    f32x4 x0 = *(const f32x4*)(r_);
    f32x4 x1 = *(const f32x4*)(r_ + 256);
    f32x4 x2 = *(const f32x4*)(r_ + 4 * FEAT_);
    f32x4 x3 = *(const f32x4*)(r_ + 4 * FEAT_ + 256);
    f32x4 x4 = *(const f32x4*)(r_ + 8 * FEAT_);
    f32x4 x5 = *(const f32x4*)(r_ + 8 * FEAT_ + 256);
    f32x4 x6 = *(const f32x4*)(r_ + 12 * FEAT_);
    f32x4 x7 = *(const f32x4*)(r_ + 12 * FEAT_ + 256);

    float p0 = dot8(x0, x1, v0, v1);
    float p1 = dot8(x2, x3, v0, v1);
    float p2 = dot8(x4, x5, v0, v1);
    float p3 = dot8(x6, x7, v0, v1);
    p0 = wredsum(p0);
    p1 = wredsum(p1);
    p2 = wredsum(p2);
    p3 = wredsum(p3);
    float mn = fmaxf(fmaxf(fmaxf(p0, p1), fmaxf(p2, p3)), m);
    float sc = __expf(m - mn);   // first group: exp(-inf)=0
    float w0 = __expf(p0 - mn), w1 = __expf(p1 - mn);
    float w2 = __expf(p2 - mn), w3 = __expf(p3 - mn);
    l = fmaf(l, sc, (w0 + w1) + (w2 + w3));
#pragma unroll
    for (int j = 0; j < 4; ++j) {
      a0[j] = fmaf(w0, x0[j],
              fmaf(w1, x2[j], fmaf(w2, x4[j], fmaf(w3, x6[j], a0[j] * sc))));
      a1[j] = fmaf(w0, x1[j],
              fmaf(w1, x3[j], fmaf(w2, x5[j], fmaf(w3, x7[j], a1[j] * sc))));
    }
    m = mn;
  }
  // tail: single row per step
  for (; s < s1; s += 4) {
    const float* r_ = base + (size_t)s * FEAT_ + lane * 4;
    f32x4 x0 = *(const f32x4*)(r_);
    f32x4 x1 = *(const f32x4*)(r_ + 256);
    float p = wredsum(dot8(x0, x1, v0, v1));
    float mn = fmaxf(m, p);
    float sc = __expf(m - mn);
    float w = __expf(p - mn);
    l = fmaf(l, sc, w);
#pragma unroll
    for (int j = 0; j < 4; ++j) {
      a0[j] = fmaf(w, x0[j], a0[j] * sc);
      a1[j] = fmaf(w, x1[j], a1[j] * sc);
    }
    m = mn;
  }

  // cross-wave combine in LDS
  __shared__ float sm[4], sl[4];
  __shared__ float sa[4][FEAT_];
  if (lane == 0) { sm[wave] = m; sl[wave] = l; }
  *(f32x4*)&sa[wave][lane * 4] = a0;
  *(f32x4*)&sa[wave][256 + lane * 4] = a1;
  __syncthreads();

  float M = fmaxf(fmaxf(sm[0], sm[1]), fmaxf(sm[2], sm[3]));
  float e0 = __expf(sm[0] - M), e1 = __expf(sm[1] - M);
  float e2 = __expf(sm[2] - M), e3 = __expf(sm[3] - M);
  if (tid == 0) {
    pm[idx] = M;
    pl[idx] = e0 * sl[0] + e1 * sl[1] + e2 * sl[2] + e3 * sl[3];
  }
  for (int f = tid; f < FEAT_; f += 256)
    pacc[(size_t)idx * FEAT_ + f] =
        e0 * sa[0][f] + e1 * sa[1][f] + e2 * sa[2][f] + e3 * sa[3][f];
}

// ---------------------------------------------------------------------------
// Kernel 3: combine partials per batch, normalize, zero L==0 rows.
// ---------------------------------------------------------------------------
__global__ __launch_bounds__(256) void combine_kernel(
    const float* __restrict__ pm, const float* __restrict__ pl,
    const float* __restrict__ pacc, float* __restrict__ out) {
  int b = blockIdx.x;
  int tid = threadIdx.x;
  __shared__ float e[NSPLIT];
  __shared__ float inv_s;
  if (tid < NSPLIT) {  // lanes 0..15 of wave 0
    float mi = pm[b * NSPLIT + tid];
    float M = mi;
#pragma unroll
    for (int off = 8; off; off >>= 1) M = fmaxf(M, __shfl_xor(M, off, 64));
    float ei = (M == -INFINITY) ? 0.f : __expf(mi - M);
    e[tid] = ei;
    float lw = ei * pl[b * NSPLIT + tid];
#pragma unroll
    for (int off = 8; off; off >>= 1) lw += __shfl_xor(lw, off, 64);
    if (tid == 0) inv_s = (lw > 0.f) ? 1.f / lw : 0.f;  // L==0 -> zeros
  }
  __syncthreads();
  float inv = inv_s;
  for (int f = tid; f < FEAT_; f += 256) {
    float s = 0.f;
    for (int i = 0; i < NSPLIT; ++i)
      if (e[i] > 0.f)   // block-uniform; skips loads of never-written pacc
        s = fmaf(e[i], pacc[((size_t)(b * NSPLIT + i)) * FEAT_ + f], s);
    out[b * FEAT_ + f] = s * inv;
  }
}

extern "C" void kernel_launch(void* const* d_in, const int* in_sizes, int n_in,
                              void* d_out, int out_size, void* d_ws, size_t ws_size,
                              hipStream_t stream) {
  const float* input_k = (const float*)d_in[0];
  const float* input_q = (const float*)d_in[1];
  const int*   ctx     = (const int*)d_in[2];
  const float* W_K     = (const float*)d_in[3];
  const float* W_Q     = (const float*)d_in[4];
  float* out = (float*)d_out;

  char* ws = (char*)d_ws;
  float* v    = (float*)ws;                                   // B*FEAT
  float* pm   = (float*)(ws + (size_t)B_ * FEAT_ * sizeof(float));
  float* pl   = pm + B_ * NSPLIT;
  float* pacc = pl + B_ * NSPLIT;                             // B*NSPLIT*FEAT

  qv_kernel<<<B_, 256, 0, stream>>>(input_q, W_Q, W_K, v);
  pass_kernel<<<dim3(NSPLIT, B_), 256, 0, stream>>>(input_k, ctx, v, pm, pl, pacc);
  combine_kernel<<<B_, 256, 0, stream>>>(pm, pl, pacc, out);
}